// Round 13
// baseline (507.423 us; speedup 1.0000x reference)
//
#include <hip/hip_runtime.h>
#include <hip/hip_bf16.h>
#include <stdint.h>

#define N_NODES 100000
#define N_EDGES 3200000
#define IN_CH 256
#define HID 128
#define EPS 1e-5f
#define BSH 9              // bucket = dst >> 9  (512 nodes per bucket)
#define NBUK 196           // ceil(100000/512)
#define PCAP 17664         // fixed bucket capacity (mean 16327, +10 sigma)
#define PCHUNK 4096
#define GEMM_GRID 782      // ceil(100000/128)

using bf16x8 = __attribute__((ext_vector_type(8))) short;
using f32x4  = __attribute__((ext_vector_type(4))) float;
using f32x2  = __attribute__((ext_vector_type(2))) float;

__device__ __forceinline__ uint32_t f2bf(float f) {
  uint32_t u = __float_as_uint(f);
  return (u + 0x7FFFu + ((u >> 16) & 1u)) >> 16;
}
__device__ __forceinline__ float bflo(uint32_t u) { return __uint_as_float(u << 16); }
__device__ __forceinline__ float bfhi(uint32_t u) { return __uint_as_float(u & 0xFFFF0000u); }

// ---- workspace layout (bytes) ----
static const size_t OFF_SRC   = 0;            // int[196*17664] padded CSR = 13,848,576
static const size_t OFF_OFFS2 = 13848576;     // int2[100000] = 800,000
static const size_t OFF_DINV  = 14648576;     // float[100000]
static const size_t OFF_WPK0  = 15048576;     // 65,536
static const size_t OFF_WPK1  = 15114112;     // 32,768
static const size_t OFF_WPK2  = 15146880;     // 32,768
static const size_t OFF_WPKR  = 15179648;     // 65,536
static const size_t OFF_FLAG  = 15245184;     // int (+pad)
static const size_t OFF_BCUR  = 15245312;     // int[NBUK] (+pad)
static const size_t OFF_H8    = 15246336;     // fp8[100001*128] = 12,800,128
static const size_t OFF_PART  = 15246336;     // int2[196*17664] = 27,697,152 (aliases H8; dead before GEMM)
static const size_t OFF_RESB  = 42943616;     // bf16[100000*128] = 25,600,000
static const size_t OFF_HBA   = 68543616;     // bf16[100000*128]
static const size_t OFF_HBB   = 94143616;     // bf16[100000*128]  (end ~119.7MB)

// ---- edge dtype detection: int64 edges have zero high words ----
__global__ void k_flag(const uint32_t* __restrict__ e, int* flag) {
  __shared__ int any;
  if (threadIdx.x == 0) any = 0;
  __syncthreads();
  uint32_t acc = 0;
  for (int i = threadIdx.x; i < 2048; i += blockDim.x) acc |= e[2 * i + 1];
  if (acc) atomicOr(&any, 1);
  __syncthreads();
  if (threadIdx.x == 0) *flag = (any == 0) ? 1 : 0;  // 1 => int64 layout
}

// ---- init static bucket cursors ----
__global__ void k_init(int* __restrict__ bcur) {
  int t = threadIdx.x;
  if (t < NBUK) bcur[t] = t * PCAP;
}

// ---- LDS-staged partition into fixed-capacity buckets (coalesced writes) ----
__global__ __launch_bounds__(256) void k_part(const void* __restrict__ eidx,
                                              const int* __restrict__ flag,
                                              int* __restrict__ bcur,
                                              int2* __restrict__ part) {
  __shared__ int lhist[NBUK];
  __shared__ int lbase[NBUK];
  __shared__ int gbase[NBUK];
  __shared__ int sm[256];
  __shared__ int2 sbuf[PCHUNK];
  __shared__ uint8_t bbuf[PCHUNK];
  int tid = threadIdx.x;
  int base = blockIdx.x * PCHUNK;
  int nE = N_EDGES - base;
  if (nE > PCHUNK) nE = PCHUNK;
  for (int t = tid; t < NBUK; t += 256) lhist[t] = 0;
  __syncthreads();
  bool i64 = (*flag != 0);
  int es[16], ed[16], ml[16];
  #pragma unroll
  for (int k = 0; k < 16; ++k) {
    int ci = k * 256 + tid;
    if (ci < nE) {
      int e = base + ci;
      int s, d;
      if (i64) {
        const uint32_t* u = (const uint32_t*)eidx;
        s = (int)u[2 * (size_t)e];
        d = (int)u[2 * ((size_t)N_EDGES + e)];
      } else {
        const int* u = (const int*)eidx;
        s = u[e];
        d = u[N_EDGES + e];
      }
      es[k] = s; ed[k] = d;
      ml[k] = atomicAdd(&lhist[d >> BSH], 1);
    }
  }
  __syncthreads();
  sm[tid] = (tid < NBUK) ? lhist[tid] : 0;
  __syncthreads();
  for (int s = 1; s < 256; s <<= 1) {
    int t = (tid >= s) ? sm[tid - s] : 0;
    __syncthreads();
    sm[tid] += t;
    __syncthreads();
  }
  if (tid < NBUK) lbase[tid] = sm[tid] - lhist[tid];
  __syncthreads();
  #pragma unroll
  for (int k = 0; k < 16; ++k) {
    int ci = k * 256 + tid;
    if (ci < nE) {
      int b = ed[k] >> BSH;
      int slot = lbase[b] + ml[k];
      sbuf[slot] = make_int2(es[k], ed[k]);
      bbuf[slot] = (uint8_t)b;
    }
  }
  if (tid < NBUK && lhist[tid] > 0) gbase[tid] = atomicAdd(&bcur[tid], lhist[tid]);
  __syncthreads();
  for (int i = tid; i < nE; i += 256) {
    int b = bbuf[i];
    part[(size_t)gbase[b] + (i - lbase[b])] = sbuf[i];
  }
}

// ---- fused bucket pass: count -> padded scan -> offs2/dinv -> scatter -> pad fill ----
__global__ __launch_bounds__(256) void k_bucket(const int2* __restrict__ part,
                                                const int* __restrict__ bcur,
                                                int2* __restrict__ offs2,
                                                float* __restrict__ dinv,
                                                int* __restrict__ sedge) {
  __shared__ int cnt[512];
  __shared__ int pre[512];
  __shared__ int cur[512];
  __shared__ int s2[256];
  int tid = threadIdx.x, b = blockIdx.x;
  int v0 = b << BSH;
  int e0 = b * PCAP;
  int e1 = bcur[b];                     // final cursor == e0 + bucket count
  cnt[tid] = 0; cnt[tid + 256] = 0;
  __syncthreads();
  for (int i = e0 + tid; i < e1; i += 256) atomicAdd(&cnt[part[i].y - v0], 1);
  __syncthreads();
  int pa = (cnt[2 * tid] + 3) & ~3, pb = (cnt[2 * tid + 1] + 3) & ~3;
  s2[tid] = pa + pb;
  __syncthreads();
  for (int s = 1; s < 256; s <<= 1) {
    int t = (tid >= s) ? s2[tid - s] : 0;
    __syncthreads();
    s2[tid] += t;
    __syncthreads();
  }
  int eb = s2[tid] - (pa + pb);
  pre[2 * tid] = eb;          cur[2 * tid] = eb;
  pre[2 * tid + 1] = eb + pa; cur[2 * tid + 1] = eb + pa;
  __syncthreads();
  #pragma unroll
  for (int k = 0; k < 2; ++k) {
    int t = tid + k * 256, v = v0 + t;
    if (v < N_NODES) {
      int c = cnt[t];
      offs2[v] = make_int2(e0 + pre[t], ((c + 3) & ~3) >> 2);
      dinv[v] = rsqrtf((float)(c + 1));
    }
  }
  __syncthreads();
  for (int i = e0 + tid; i < e1; i += 256) {
    int2 e = part[i];
    int p = atomicAdd(&cur[e.y - v0], 1);
    sedge[e0 + p] = e.x;
  }
  __syncthreads();
  #pragma unroll
  for (int k = 0; k < 2; ++k) {
    int t = tid + k * 256, v = v0 + t;
    if (v < N_NODES) {
      int endx = cur[t];
      int endp = pre[t] + ((endx - pre[t] + 3) & ~3);
      for (int u = endx; u < endp; ++u) sedge[e0 + u] = N_NODES;  // sentinel row
    }
  }
}

// pack W [K][HID] f32 row-major into MFMA B-fragment-ready bf16 layout
__global__ void k_packW(const float* __restrict__ W, uint16_t* __restrict__ Wp, int K) {
  int t = blockIdx.x * blockDim.x + threadIdx.x;
  int total = (K / 32) * 8 * 64;
  if (t >= total) return;
  int l = t & 63;
  int nt = (t >> 6) & 7;
  int ks = t >> 9;
  int kbase = ks * 32 + (l >> 4) * 8;
  int col = nt * 16 + (l & 15);
  #pragma unroll
  for (int j = 0; j < 8; ++j)
    Wp[(size_t)t * 8 + j] = (uint16_t)f2bf(W[(size_t)(kbase + j) * HID + col]);
}

// epilogue: store h' = dinv[row] * acc as fp8 e4m3 rows, via swizzled LDS repack
__device__ __forceinline__ void epilogue_fp8(const f32x4* acc, int l, int row0,
                                             uint8_t* lds_my,
                                             uint8_t* __restrict__ H8,
                                             const float* __restrict__ dinv) {
  float dv[4];
  #pragma unroll
  for (int j = 0; j < 4; ++j) {
    int r = row0 + (l >> 4) * 4 + j;
    dv[j] = dinv[min(r, N_NODES - 1)];
  }
  #pragma unroll
  for (int nt = 0; nt < 8; ++nt)
    #pragma unroll
    for (int j = 0; j < 4; ++j) {
      int r = (l >> 4) * 4 + j, c = nt * 16 + (l & 15);
      uint32_t pk = __builtin_amdgcn_cvt_pk_fp8_f32(acc[nt][j] * dv[j], 0.f, 0u, false);
      lds_my[r * 128 + (c ^ ((r & 7) << 2))] = (uint8_t)pk;  // 4B-granule swizzle by row
    }
  asm volatile("s_waitcnt lgkmcnt(0)" ::: "memory");
  int r = l >> 2;
  uint32_t w[8];
  #pragma unroll
  for (int t = 0; t < 8; ++t) {
    int c4 = (l & 3) * 8 + t;
    w[t] = *(const uint32_t*)(lds_my + r * 128 + ((c4 ^ (r & 7)) << 2));
  }
  if (row0 + r < N_NODES) {
    uint4* gp = (uint4*)(H8 + (size_t)(row0 + r) * 128 + (l & 3) * 32);
    gp[0] = make_uint4(w[0], w[1], w[2], w[3]);
    gp[1] = make_uint4(w[4], w[5], w[6], w[7]);
  }
  asm volatile("s_waitcnt lgkmcnt(0)" ::: "memory");
}

// layer-0 fused dual GEMM in one launch: blocks [0,782) do X@W0 -> fp8 h';
// blocks [782,1564) do X@Wr -> bf16 residual. f32 A read + in-flight cvt.
__global__ __launch_bounds__(256) void k_gemm0d(const float* __restrict__ X,
                                                const uint16_t* __restrict__ Wp0,
                                                const uint16_t* __restrict__ WpR,
                                                uint8_t* __restrict__ H8,
                                                const float* __restrict__ dinv,
                                                uint16_t* __restrict__ resB) {
  __shared__ __align__(16) char smem[32768];
  int tid = threadIdx.x, wid = tid >> 6, l = tid & 63;
  bool second = blockIdx.x >= GEMM_GRID;
  int blk = second ? (blockIdx.x - GEMM_GRID) : blockIdx.x;
  const uint16_t* Wp = second ? WpR : Wp0;
  int r0 = blk * 128 + wid * 32;
  int hk = l >> 4, rl = l & 15;
  int ra0 = min(r0 + rl, N_NODES - 1);
  int ra1 = min(r0 + 16 + rl, N_NODES - 1);
  f32x4 acc[2][8] = {};
  #pragma unroll
  for (int kh = 0; kh < 2; ++kh) {
    __syncthreads();
    #pragma unroll
    for (int i = 0; i < 8; ++i) {
      int gidx = i * 256 + tid;
      *(uint4*)(smem + gidx * 16) =
          *(const uint4*)((const char*)Wp + (size_t)kh * 32768 + gidx * 16);
    }
    __syncthreads();
    #pragma unroll
    for (int ksl = 0; ksl < 4; ++ksl) {
      int kof = kh * 128 + ksl * 32 + hk * 8;
      float4 u0 = *(const float4*)(X + (size_t)ra0 * 256 + kof);
      float4 u1 = *(const float4*)(X + (size_t)ra0 * 256 + kof + 4);
      float4 w0 = *(const float4*)(X + (size_t)ra1 * 256 + kof);
      float4 w1 = *(const float4*)(X + (size_t)ra1 * 256 + kof + 4);
      bf16x8 a0, a1;
      a0[0] = (short)f2bf(u0.x); a0[1] = (short)f2bf(u0.y);
      a0[2] = (short)f2bf(u0.z); a0[3] = (short)f2bf(u0.w);
      a0[4] = (short)f2bf(u1.x); a0[5] = (short)f2bf(u1.y);
      a0[6] = (short)f2bf(u1.z); a0[7] = (short)f2bf(u1.w);
      a1[0] = (short)f2bf(w0.x); a1[1] = (short)f2bf(w0.y);
      a1[2] = (short)f2bf(w0.z); a1[3] = (short)f2bf(w0.w);
      a1[4] = (short)f2bf(w1.x); a1[5] = (short)f2bf(w1.y);
      a1[6] = (short)f2bf(w1.z); a1[7] = (short)f2bf(w1.w);
      #pragma unroll
      for (int nt = 0; nt < 8; ++nt) {
        bf16x8 b = *(const bf16x8*)(smem + ((ksl * 8 + nt) * 64 + l) * 16);
        acc[0][nt] = __builtin_amdgcn_mfma_f32_16x16x32_bf16(a0, b, acc[0][nt], 0, 0, 0);
        acc[1][nt] = __builtin_amdgcn_mfma_f32_16x16x32_bf16(a1, b, acc[1][nt], 0, 0, 0);
      }
    }
  }
  __syncthreads();  // B dead; per-wave epilogue scratch (8KB each)
  if (!second) {
    uint8_t* lds8 = (uint8_t*)(smem + wid * 8192);
    epilogue_fp8(acc[0], l, r0, lds8, H8, dinv);
    epilogue_fp8(acc[1], l, r0 + 16, lds8, H8, dinv);
  } else {
    uint16_t* ldsb = (uint16_t*)(smem + wid * 8192);
    #pragma unroll
    for (int rt = 0; rt < 2; ++rt) {
      int row0 = r0 + rt * 16;
      #pragma unroll
      for (int nt = 0; nt < 8; ++nt)
        #pragma unroll
        for (int j = 0; j < 4; ++j)
          ldsb[((l >> 4) * 4 + j) * 128 + nt * 16 + (l & 15)] = (uint16_t)f2bf(acc[rt][nt][j]);
      asm volatile("s_waitcnt lgkmcnt(0)" ::: "memory");
      const uint4* sb = (const uint4*)ldsb;
      if (row0 + (l >> 2) < N_NODES) {
        uint4* gb = (uint4*)(resB + (size_t)(row0 + (l >> 2)) * 128 + (l & 3) * 32);
        #pragma unroll
        for (int t = 0; t < 4; ++t) gb[t] = sb[l * 4 + t];
      }
      asm volatile("s_waitcnt lgkmcnt(0)" ::: "memory");
    }
  }
}

// layers 1/2 GEMM: A bf16 [N][128] @ Wp(LDS-shared) -> fp8 h'
__global__ __launch_bounds__(256) void k_gemm8(const uint16_t* __restrict__ A,
                                               const uint16_t* __restrict__ Wp,
                                               uint8_t* __restrict__ H8,
                                               const float* __restrict__ dinv) {
  __shared__ __align__(16) char smem[32768];
  int tid = threadIdx.x, wid = tid >> 6, l = tid & 63;
  #pragma unroll
  for (int i = 0; i < 8; ++i) {
    int gidx = i * 256 + tid;
    *(uint4*)(smem + gidx * 16) = *(const uint4*)((const char*)Wp + gidx * 16);
  }
  __syncthreads();
  int r0 = blockIdx.x * 128 + wid * 32;
  int hk = l >> 4, rl = l & 15;
  int ra0 = min(r0 + rl, N_NODES - 1);
  int ra1 = min(r0 + 16 + rl, N_NODES - 1);
  f32x4 acc[2][8] = {};
  #pragma unroll
  for (int ks = 0; ks < 4; ++ks) {
    bf16x8 a0 = *(const bf16x8*)(A + (size_t)ra0 * 128 + ks * 32 + hk * 8);
    bf16x8 a1 = *(const bf16x8*)(A + (size_t)ra1 * 128 + ks * 32 + hk * 8);
    #pragma unroll
    for (int nt = 0; nt < 8; ++nt) {
      bf16x8 b = *(const bf16x8*)(smem + ((ks * 8 + nt) * 64 + l) * 16);
      acc[0][nt] = __builtin_amdgcn_mfma_f32_16x16x32_bf16(a0, b, acc[0][nt], 0, 0, 0);
      acc[1][nt] = __builtin_amdgcn_mfma_f32_16x16x32_bf16(a1, b, acc[1][nt], 0, 0, 0);
    }
  }
  __syncthreads();  // B dead; reuse as epilogue scratch
  uint8_t* lds8 = (uint8_t*)(smem + wid * 4096);
  epilogue_fp8(acc[0], l, r0, lds8, H8, dinv);
  epilogue_fp8(acc[1], l, r0 + 16, lds8, H8, dinv);
}

// fused: fp8 gather-sum + bias + LN + ReLU + bf16 residual
// eight 8-lane groups; group o owns 4-edge blocks jb%8==o (uint4 index loads);
// lane owns 16 channels (uint4 gather = 16B); unweighted fp8 row sum.
#define PROC16(H)                                                      \
  do {                                                                 \
    f32x2 f_;                                                          \
    f_ = __builtin_amdgcn_cvt_pk_f32_fp8((H).x, false);                \
    asm("v_pk_add_f32 %0, %0, %1" : "+v"(A0) : "v"(f_));               \
    f_ = __builtin_amdgcn_cvt_pk_f32_fp8((H).x, true);                 \
    asm("v_pk_add_f32 %0, %0, %1" : "+v"(A1) : "v"(f_));               \
    f_ = __builtin_amdgcn_cvt_pk_f32_fp8((H).y, false);                \
    asm("v_pk_add_f32 %0, %0, %1" : "+v"(A2) : "v"(f_));               \
    f_ = __builtin_amdgcn_cvt_pk_f32_fp8((H).y, true);                 \
    asm("v_pk_add_f32 %0, %0, %1" : "+v"(A3) : "v"(f_));               \
    f_ = __builtin_amdgcn_cvt_pk_f32_fp8((H).z, false);                \
    asm("v_pk_add_f32 %0, %0, %1" : "+v"(A4) : "v"(f_));               \
    f_ = __builtin_amdgcn_cvt_pk_f32_fp8((H).z, true);                 \
    asm("v_pk_add_f32 %0, %0, %1" : "+v"(A5) : "v"(f_));               \
    f_ = __builtin_amdgcn_cvt_pk_f32_fp8((H).w, false);                \
    asm("v_pk_add_f32 %0, %0, %1" : "+v"(A6) : "v"(f_));               \
    f_ = __builtin_amdgcn_cvt_pk_f32_fp8((H).w, true);                 \
    asm("v_pk_add_f32 %0, %0, %1" : "+v"(A7) : "v"(f_));               \
  } while (0)

__global__ __launch_bounds__(256) void k_agg(const uint8_t* __restrict__ H8,
                                             const int* __restrict__ sedge,
                                             const int2* __restrict__ offs2,
                                             const float* __restrict__ dinv,
                                             const float* __restrict__ bias,
                                             const float* __restrict__ g,
                                             const float* __restrict__ be,
                                             const uint16_t* __restrict__ residB,
                                             float* __restrict__ outF,
                                             uint16_t* __restrict__ outB) {
  int wid = threadIdx.x >> 6, l = threadIdx.x & 63;
  int v = blockIdx.x * 4 + wid;
  if (v >= N_NODES) return;
  int o = l >> 3, c8 = l & 7;
  uint32_t coff = (uint32_t)c8 << 4;   // 16B slice per lane
  f32x2 A0 = {0.f, 0.f}, A1 = {0.f, 0.f}, A2 = {0.f, 0.f}, A3 = {0.f, 0.f};
  f32x2 A4 = {0.f, 0.f}, A5 = {0.f, 0.f}, A6 = {0.f, 0.f}, A7 = {0.f, 0.f};
  int2 ofs = offs2[v];
  int nb = ofs.y;                        // 4-edge blocks (padded, exact)
  const uint4* sblk = (const uint4*)(sedge + ofs.x);
  int jb = o;
  for (; jb + 8 < nb; jb += 16) {
    uint4 i0 = sblk[jb];
    uint4 i1 = sblk[jb + 8];
    uint4 h0 = *(const uint4*)(H8 + ((i0.x << 7) | coff));
    uint4 h1 = *(const uint4*)(H8 + ((i0.y << 7) | coff));
    uint4 h2 = *(const uint4*)(H8 + ((i0.z << 7) | coff));
    uint4 h3 = *(const uint4*)(H8 + ((i0.w << 7) | coff));
    uint4 h4 = *(const uint4*)(H8 + ((i1.x << 7) | coff));
    uint4 h5 = *(const uint4*)(H8 + ((i1.y << 7) | coff));
    uint4 h6 = *(const uint4*)(H8 + ((i1.z << 7) | coff));
    uint4 h7 = *(const uint4*)(H8 + ((i1.w << 7) | coff));
    PROC16(h0); PROC16(h1); PROC16(h2); PROC16(h3);
    PROC16(h4); PROC16(h5); PROC16(h6); PROC16(h7);
  }
  for (; jb < nb; jb += 8) {
    uint4 i0 = sblk[jb];
    uint4 h0 = *(const uint4*)(H8 + ((i0.x << 7) | coff));
    uint4 h1 = *(const uint4*)(H8 + ((i0.y << 7) | coff));
    uint4 h2 = *(const uint4*)(H8 + ((i0.z << 7) | coff));
    uint4 h3 = *(const uint4*)(H8 + ((i0.w << 7) | coff));
    PROC16(h0); PROC16(h1); PROC16(h2); PROC16(h3);
  }
  if (o == 0) {  // self loop: + own h' row (once, group 0)
    uint4 h = *(const uint4*)(H8 + (((uint32_t)v << 7) | coff));
    PROC16(h);
  }
  // combine the 8 groups (masks 8,16,32)
  #pragma unroll
  for (int m = 8; m <= 32; m <<= 1) {
    A0.x += __shfl_xor(A0.x, m, 64); A0.y += __shfl_xor(A0.y, m, 64);
    A1.x += __shfl_xor(A1.x, m, 64); A1.y += __shfl_xor(A1.y, m, 64);
    A2.x += __shfl_xor(A2.x, m, 64); A2.y += __shfl_xor(A2.y, m, 64);
    A3.x += __shfl_xor(A3.x, m, 64); A3.y += __shfl_xor(A3.y, m, 64);
    A4.x += __shfl_xor(A4.x, m, 64); A4.y += __shfl_xor(A4.y, m, 64);
    A5.x += __shfl_xor(A5.x, m, 64); A5.y += __shfl_xor(A5.y, m, 64);
    A6.x += __shfl_xor(A6.x, m, 64); A6.y += __shfl_xor(A6.y, m, 64);
    A7.x += __shfl_xor(A7.x, m, 64); A7.y += __shfl_xor(A7.y, m, 64);
  }
  float a[16] = {A0.x, A0.y, A1.x, A1.y, A2.x, A2.y, A3.x, A3.y,
                 A4.x, A4.y, A5.x, A5.y, A6.x, A6.y, A7.x, A7.y};
  float dv = dinv[v];
  const float4* bp = (const float4*)(bias + c8 * 16);
  #pragma unroll
  for (int w = 0; w < 4; ++w) {
    float4 bb = bp[w];
    a[4 * w + 0] = dv * a[4 * w + 0] + bb.x;
    a[4 * w + 1] = dv * a[4 * w + 1] + bb.y;
    a[4 * w + 2] = dv * a[4 * w + 2] + bb.z;
    a[4 * w + 3] = dv * a[4 * w + 3] + bb.w;
  }
  // LayerNorm over 128 channels (8-lane reduction within group; groups identical)
  float s = 0.f;
  #pragma unroll
  for (int i = 0; i < 16; ++i) s += a[i];
  #pragma unroll
  for (int m = 1; m < 8; m <<= 1) s += __shfl_xor(s, m, 64);
  float mu = s * (1.f / 128.f);
  float qq = 0.f;
  #pragma unroll
  for (int i = 0; i < 16; ++i) {
    a[i] -= mu;
    qq += a[i] * a[i];
  }
  #pragma unroll
  for (int m = 1; m < 8; m <<= 1) qq += __shfl_xor(qq, m, 64);
  float rs = rsqrtf(qq * (1.f / 128.f) + EPS);
  if (o == 0) {
    const float4* gp = (const float4*)(g + c8 * 16);
    const float4* ep = (const float4*)(be + c8 * 16);
    const uint4* rp = (const uint4*)(residB + (size_t)v * 128 + c8 * 16);
    uint4 rr0 = rp[0], rr1 = rp[1];
    float y[16];
    #pragma unroll
    for (int w = 0; w < 4; ++w) {
      float4 gg = gp[w];
      float4 ee = ep[w];
      y[4 * w + 0] = fmaxf(a[4 * w + 0] * rs * gg.x + ee.x, 0.f);
      y[4 * w + 1] = fmaxf(a[4 * w + 1] * rs * gg.y + ee.y, 0.f);
      y[4 * w + 2] = fmaxf(a[4 * w + 2] * rs * gg.z + ee.z, 0.f);
      y[4 * w + 3] = fmaxf(a[4 * w + 3] * rs * gg.w + ee.w, 0.f);
    }
    y[0] += bflo(rr0.x);  y[1] += bfhi(rr0.x);
    y[2] += bflo(rr0.y);  y[3] += bfhi(rr0.y);
    y[4] += bflo(rr0.z);  y[5] += bfhi(rr0.z);
    y[6] += bflo(rr0.w);  y[7] += bfhi(rr0.w);
    y[8] += bflo(rr1.x);  y[9] += bfhi(rr1.x);
    y[10] += bflo(rr1.y); y[11] += bfhi(rr1.y);
    y[12] += bflo(rr1.z); y[13] += bfhi(rr1.z);
    y[14] += bflo(rr1.w); y[15] += bfhi(rr1.w);
    if (outF) {
      float* op = outF + (size_t)v * HID + c8 * 16;
      #pragma unroll
      for (int w = 0; w < 4; ++w)
        *(float4*)(op + 4 * w) = make_float4(y[4 * w], y[4 * w + 1], y[4 * w + 2], y[4 * w + 3]);
    }
    if (outB) {
      uint4 o0, o1;
      o0.x = f2bf(y[0]) | (f2bf(y[1]) << 16);
      o0.y = f2bf(y[2]) | (f2bf(y[3]) << 16);
      o0.z = f2bf(y[4]) | (f2bf(y[5]) << 16);
      o0.w = f2bf(y[6]) | (f2bf(y[7]) << 16);
      o1.x = f2bf(y[8]) | (f2bf(y[9]) << 16);
      o1.y = f2bf(y[10]) | (f2bf(y[11]) << 16);
      o1.z = f2bf(y[12]) | (f2bf(y[13]) << 16);
      o1.w = f2bf(y[14]) | (f2bf(y[15]) << 16);
      uint4* obp = (uint4*)(outB + (size_t)v * 128 + c8 * 16);
      obp[0] = o0;
      obp[1] = o1;
    }
  }
}

extern "C" void kernel_launch(void* const* d_in, const int* in_sizes, int n_in,
                              void* d_out, int out_size, void* d_ws, size_t ws_size,
                              hipStream_t stream) {
  const float* x   = (const float*)d_in[0];
  const void*  ei  = d_in[1];
  const float* W0  = (const float*)d_in[2];
  const float* b0  = (const float*)d_in[3];
  const float* g0  = (const float*)d_in[4];
  const float* be0 = (const float*)d_in[5];
  const float* W1  = (const float*)d_in[6];
  const float* b1  = (const float*)d_in[7];
  const float* g1  = (const float*)d_in[8];
  const float* be1 = (const float*)d_in[9];
  const float* W2  = (const float*)d_in[10];
  const float* b2  = (const float*)d_in[11];
  const float* g2  = (const float*)d_in[12];
  const float* be2 = (const float*)d_in[13];
  const float* Wr  = (const float*)d_in[14];

  char* ws = (char*)d_ws;
  int*      sedge  = (int*)(ws + OFF_SRC);
  int2*     offs2  = (int2*)(ws + OFF_OFFS2);
  float*    dinv   = (float*)(ws + OFF_DINV);
  uint16_t* wpk0   = (uint16_t*)(ws + OFF_WPK0);
  uint16_t* wpk1   = (uint16_t*)(ws + OFF_WPK1);
  uint16_t* wpk2   = (uint16_t*)(ws + OFF_WPK2);
  uint16_t* wpkr   = (uint16_t*)(ws + OFF_WPKR);
  int*      flag   = (int*)(ws + OFF_FLAG);
  int*      bcur   = (int*)(ws + OFF_BCUR);
  uint8_t*  h8     = (uint8_t*)(ws + OFF_H8);
  int2*     part   = (int2*)(ws + OFF_PART);
  uint16_t* resB   = (uint16_t*)(ws + OFF_RESB);
  uint16_t* hbA    = (uint16_t*)(ws + OFF_HBA);
  uint16_t* hbB    = (uint16_t*)(ws + OFF_HBB);
  float*    out    = (float*)d_out;

  // ---- edge preprocessing: partition (fixed-cap buckets) -> fused bucket CSR ----
  k_flag<<<1, 256, 0, stream>>>((const uint32_t*)ei, flag);
  k_init<<<1, 256, 0, stream>>>(bcur);
  k_part<<<(N_EDGES + PCHUNK - 1) / PCHUNK, 256, 0, stream>>>(ei, flag, bcur, part);
  k_bucket<<<NBUK, 256, 0, stream>>>(part, bcur, offs2, dinv, sedge);
  // sentinel row (src == N_NODES) must be zero; part buffer is dead now
  hipMemsetAsync(h8 + (size_t)N_NODES * 128, 0, 128, stream);

  // ---- weight packing ----
  k_packW<<<16, 256, 0, stream>>>(W0, wpk0, IN_CH);
  k_packW<<<8, 256, 0, stream>>>(W1, wpk1, HID);
  k_packW<<<8, 256, 0, stream>>>(W2, wpk2, HID);
  k_packW<<<16, 256, 0, stream>>>(Wr, wpkr, IN_CH);

  // ---- layer 0: fused dual K=256 GEMM launch (x@W0 -> fp8 h', x@Wr -> bf16 resid) ----
  k_gemm0d<<<2 * GEMM_GRID, 256, 0, stream>>>(x, wpk0, wpkr, h8, dinv, resB);
  k_agg<<<25000, 256, 0, stream>>>(h8, sedge, offs2, dinv, b0, g0, be0, resB, nullptr, hbA);

  // ---- layer 1 ----
  k_gemm8<<<GEMM_GRID, 256, 0, stream>>>(hbA, wpk1, h8, dinv);
  k_agg<<<25000, 256, 0, stream>>>(h8, sedge, offs2, dinv, b1, g1, be1, hbA, nullptr, hbB);

  // ---- layer 2 (writes d_out f32) ----
  k_gemm8<<<GEMM_GRID, 256, 0, stream>>>(hbB, wpk2, h8, dinv);
  k_agg<<<25000, 256, 0, stream>>>(h8, sedge, offs2, dinv, b2, g2, be2, hbB, out, nullptr);

  (void)in_sizes; (void)n_in; (void)out_size; (void)ws_size;
}

// Round 14
// 394.040 us; speedup vs baseline: 1.2877x; 1.2877x over previous
//
#include <hip/hip_runtime.h>
#include <hip/hip_bf16.h>
#include <stdint.h>

#define N_NODES 100000
#define N_EDGES 3200000
#define IN_CH 256
#define HID 128
#define EPS 1e-5f
#define BSH 9              // bucket = dst >> 9  (512 nodes per bucket)
#define NBUK 196           // ceil(100000/512)
#define PCAP 17664         // fixed bucket capacity (mean 16327, +10 sigma)
#define PCHUNK 4096
#define GEMM_GRID 782      // ceil(100000/128)

using bf16x8 = __attribute__((ext_vector_type(8))) short;
using f32x4  = __attribute__((ext_vector_type(4))) float;
using f32x2  = __attribute__((ext_vector_type(2))) float;

__device__ __forceinline__ uint32_t f2bf(float f) {
  uint32_t u = __float_as_uint(f);
  return (u + 0x7FFFu + ((u >> 16) & 1u)) >> 16;
}
__device__ __forceinline__ float bflo(uint32_t u) { return __uint_as_float(u << 16); }
__device__ __forceinline__ float bfhi(uint32_t u) { return __uint_as_float(u & 0xFFFF0000u); }

// ---- workspace layout (bytes) ----
static const size_t OFF_SRC   = 0;            // int[196*17664] padded CSR = 13,848,576
static const size_t OFF_OFFS2 = 13848576;     // int2[100000] = 800,000
static const size_t OFF_DINV  = 14648576;     // float[100000]
static const size_t OFF_WPK0  = 15048576;     // 65,536
static const size_t OFF_WPK1  = 15114112;     // 32,768
static const size_t OFF_WPK2  = 15146880;     // 32,768
static const size_t OFF_WPKR  = 15179648;     // 65,536
static const size_t OFF_FLAG  = 15245184;     // int (+pad)
static const size_t OFF_BCUR  = 15245312;     // int[NBUK] (+pad)
static const size_t OFF_H8    = 15246336;     // fp8[100001*128] = 12,800,128
static const size_t OFF_PART  = 15246336;     // int2[196*17664] = 27,697,152 (aliases H8; dead before GEMM)
static const size_t OFF_RESB  = 42943616;     // bf16[100000*128] = 25,600,000
static const size_t OFF_HBA   = 68543616;     // bf16[100000*128]
static const size_t OFF_HBB   = 94143616;     // bf16[100000*128]  (end ~119.7MB)

// ---- edge dtype detection: int64 edges have zero high words ----
__global__ void k_flag(const uint32_t* __restrict__ e, int* flag) {
  __shared__ int any;
  if (threadIdx.x == 0) any = 0;
  __syncthreads();
  uint32_t acc = 0;
  for (int i = threadIdx.x; i < 2048; i += blockDim.x) acc |= e[2 * i + 1];
  if (acc) atomicOr(&any, 1);
  __syncthreads();
  if (threadIdx.x == 0) *flag = (any == 0) ? 1 : 0;  // 1 => int64 layout
}

// ---- init static bucket cursors ----
__global__ void k_init(int* __restrict__ bcur) {
  int t = threadIdx.x;
  if (t < NBUK) bcur[t] = t * PCAP;
}

// ---- LDS-staged partition into fixed-capacity buckets (coalesced writes) ----
__global__ __launch_bounds__(256) void k_part(const void* __restrict__ eidx,
                                              const int* __restrict__ flag,
                                              int* __restrict__ bcur,
                                              int2* __restrict__ part) {
  __shared__ int lhist[NBUK];
  __shared__ int lbase[NBUK];
  __shared__ int gbase[NBUK];
  __shared__ int sm[256];
  __shared__ int2 sbuf[PCHUNK];
  __shared__ uint8_t bbuf[PCHUNK];
  int tid = threadIdx.x;
  int base = blockIdx.x * PCHUNK;
  int nE = N_EDGES - base;
  if (nE > PCHUNK) nE = PCHUNK;
  for (int t = tid; t < NBUK; t += 256) lhist[t] = 0;
  __syncthreads();
  bool i64 = (*flag != 0);
  int es[16], ed[16], ml[16];
  #pragma unroll
  for (int k = 0; k < 16; ++k) {
    int ci = k * 256 + tid;
    if (ci < nE) {
      int e = base + ci;
      int s, d;
      if (i64) {
        const uint32_t* u = (const uint32_t*)eidx;
        s = (int)u[2 * (size_t)e];
        d = (int)u[2 * ((size_t)N_EDGES + e)];
      } else {
        const int* u = (const int*)eidx;
        s = u[e];
        d = u[N_EDGES + e];
      }
      es[k] = s; ed[k] = d;
      ml[k] = atomicAdd(&lhist[d >> BSH], 1);
    }
  }
  __syncthreads();
  sm[tid] = (tid < NBUK) ? lhist[tid] : 0;
  __syncthreads();
  for (int s = 1; s < 256; s <<= 1) {
    int t = (tid >= s) ? sm[tid - s] : 0;
    __syncthreads();
    sm[tid] += t;
    __syncthreads();
  }
  if (tid < NBUK) lbase[tid] = sm[tid] - lhist[tid];
  __syncthreads();
  #pragma unroll
  for (int k = 0; k < 16; ++k) {
    int ci = k * 256 + tid;
    if (ci < nE) {
      int b = ed[k] >> BSH;
      int slot = lbase[b] + ml[k];
      sbuf[slot] = make_int2(es[k], ed[k]);
      bbuf[slot] = (uint8_t)b;
    }
  }
  if (tid < NBUK && lhist[tid] > 0) gbase[tid] = atomicAdd(&bcur[tid], lhist[tid]);
  __syncthreads();
  for (int i = tid; i < nE; i += 256) {
    int b = bbuf[i];
    part[(size_t)gbase[b] + (i - lbase[b])] = sbuf[i];
  }
}

// ---- fused bucket pass: count -> padded scan -> offs2/dinv -> scatter -> pad fill ----
__global__ __launch_bounds__(256) void k_bucket(const int2* __restrict__ part,
                                                const int* __restrict__ bcur,
                                                int2* __restrict__ offs2,
                                                float* __restrict__ dinv,
                                                int* __restrict__ sedge) {
  __shared__ int cnt[512];
  __shared__ int pre[512];
  __shared__ int cur[512];
  __shared__ int s2[256];
  int tid = threadIdx.x, b = blockIdx.x;
  int v0 = b << BSH;
  int e0 = b * PCAP;
  int e1 = bcur[b];                     // final cursor == e0 + bucket count
  cnt[tid] = 0; cnt[tid + 256] = 0;
  __syncthreads();
  for (int i = e0 + tid; i < e1; i += 256) atomicAdd(&cnt[part[i].y - v0], 1);
  __syncthreads();
  int pa = (cnt[2 * tid] + 3) & ~3, pb = (cnt[2 * tid + 1] + 3) & ~3;
  s2[tid] = pa + pb;
  __syncthreads();
  for (int s = 1; s < 256; s <<= 1) {
    int t = (tid >= s) ? s2[tid - s] : 0;
    __syncthreads();
    s2[tid] += t;
    __syncthreads();
  }
  int eb = s2[tid] - (pa + pb);
  pre[2 * tid] = eb;          cur[2 * tid] = eb;
  pre[2 * tid + 1] = eb + pa; cur[2 * tid + 1] = eb + pa;
  __syncthreads();
  #pragma unroll
  for (int k = 0; k < 2; ++k) {
    int t = tid + k * 256, v = v0 + t;
    if (v < N_NODES) {
      int c = cnt[t];
      offs2[v] = make_int2(e0 + pre[t], ((c + 3) & ~3) >> 2);
      dinv[v] = rsqrtf((float)(c + 1));
    }
  }
  __syncthreads();
  for (int i = e0 + tid; i < e1; i += 256) {
    int2 e = part[i];
    int p = atomicAdd(&cur[e.y - v0], 1);
    sedge[e0 + p] = e.x;
  }
  __syncthreads();
  #pragma unroll
  for (int k = 0; k < 2; ++k) {
    int t = tid + k * 256, v = v0 + t;
    if (v < N_NODES) {
      int endx = cur[t];
      int endp = pre[t] + ((endx - pre[t] + 3) & ~3);
      for (int u = endx; u < endp; ++u) sedge[e0 + u] = N_NODES;  // sentinel row
    }
  }
}

// pack W [K][HID] f32 row-major into MFMA B-fragment-ready bf16 layout
__global__ void k_packW(const float* __restrict__ W, uint16_t* __restrict__ Wp, int K) {
  int t = blockIdx.x * blockDim.x + threadIdx.x;
  int total = (K / 32) * 8 * 64;
  if (t >= total) return;
  int l = t & 63;
  int nt = (t >> 6) & 7;
  int ks = t >> 9;
  int kbase = ks * 32 + (l >> 4) * 8;
  int col = nt * 16 + (l & 15);
  #pragma unroll
  for (int j = 0; j < 8; ++j)
    Wp[(size_t)t * 8 + j] = (uint16_t)f2bf(W[(size_t)(kbase + j) * HID + col]);
}

// epilogue: store h' = dinv[row] * acc as fp8 e4m3 rows, via swizzled LDS repack
__device__ __forceinline__ void epilogue_fp8(const f32x4* acc, int l, int row0,
                                             uint8_t* lds_my,
                                             uint8_t* __restrict__ H8,
                                             const float* __restrict__ dinv) {
  float dv[4];
  #pragma unroll
  for (int j = 0; j < 4; ++j) {
    int r = row0 + (l >> 4) * 4 + j;
    dv[j] = dinv[min(r, N_NODES - 1)];
  }
  #pragma unroll
  for (int nt = 0; nt < 8; ++nt)
    #pragma unroll
    for (int j = 0; j < 4; ++j) {
      int r = (l >> 4) * 4 + j, c = nt * 16 + (l & 15);
      uint32_t pk = __builtin_amdgcn_cvt_pk_fp8_f32(acc[nt][j] * dv[j], 0.f, 0u, false);
      lds_my[r * 128 + (c ^ ((r & 7) << 2))] = (uint8_t)pk;  // 4B-granule swizzle by row
    }
  asm volatile("s_waitcnt lgkmcnt(0)" ::: "memory");
  int r = l >> 2;
  uint32_t w[8];
  #pragma unroll
  for (int t = 0; t < 8; ++t) {
    int c4 = (l & 3) * 8 + t;
    w[t] = *(const uint32_t*)(lds_my + r * 128 + ((c4 ^ (r & 7)) << 2));
  }
  if (row0 + r < N_NODES) {
    uint4* gp = (uint4*)(H8 + (size_t)(row0 + r) * 128 + (l & 3) * 32);
    gp[0] = make_uint4(w[0], w[1], w[2], w[3]);
    gp[1] = make_uint4(w[4], w[5], w[6], w[7]);
  }
  asm volatile("s_waitcnt lgkmcnt(0)" ::: "memory");
}

// layer-0 fused dual GEMM in one launch: blocks [0,782) do X@W0 -> fp8 h';
// blocks [782,1564) do X@Wr -> bf16 residual. f32 A read + in-flight cvt.
__global__ __launch_bounds__(256) void k_gemm0d(const float* __restrict__ X,
                                                const uint16_t* __restrict__ Wp0,
                                                const uint16_t* __restrict__ WpR,
                                                uint8_t* __restrict__ H8,
                                                const float* __restrict__ dinv,
                                                uint16_t* __restrict__ resB) {
  __shared__ __align__(16) char smem[32768];
  int tid = threadIdx.x, wid = tid >> 6, l = tid & 63;
  bool second = blockIdx.x >= GEMM_GRID;
  int blk = second ? (blockIdx.x - GEMM_GRID) : blockIdx.x;
  const uint16_t* Wp = second ? WpR : Wp0;
  int r0 = blk * 128 + wid * 32;
  int hk = l >> 4, rl = l & 15;
  int ra0 = min(r0 + rl, N_NODES - 1);
  int ra1 = min(r0 + 16 + rl, N_NODES - 1);
  f32x4 acc[2][8] = {};
  #pragma unroll
  for (int kh = 0; kh < 2; ++kh) {
    __syncthreads();
    #pragma unroll
    for (int i = 0; i < 8; ++i) {
      int gidx = i * 256 + tid;
      *(uint4*)(smem + gidx * 16) =
          *(const uint4*)((const char*)Wp + (size_t)kh * 32768 + gidx * 16);
    }
    __syncthreads();
    #pragma unroll
    for (int ksl = 0; ksl < 4; ++ksl) {
      int kof = kh * 128 + ksl * 32 + hk * 8;
      float4 u0 = *(const float4*)(X + (size_t)ra0 * 256 + kof);
      float4 u1 = *(const float4*)(X + (size_t)ra0 * 256 + kof + 4);
      float4 w0 = *(const float4*)(X + (size_t)ra1 * 256 + kof);
      float4 w1 = *(const float4*)(X + (size_t)ra1 * 256 + kof + 4);
      bf16x8 a0, a1;
      a0[0] = (short)f2bf(u0.x); a0[1] = (short)f2bf(u0.y);
      a0[2] = (short)f2bf(u0.z); a0[3] = (short)f2bf(u0.w);
      a0[4] = (short)f2bf(u1.x); a0[5] = (short)f2bf(u1.y);
      a0[6] = (short)f2bf(u1.z); a0[7] = (short)f2bf(u1.w);
      a1[0] = (short)f2bf(w0.x); a1[1] = (short)f2bf(w0.y);
      a1[2] = (short)f2bf(w0.z); a1[3] = (short)f2bf(w0.w);
      a1[4] = (short)f2bf(w1.x); a1[5] = (short)f2bf(w1.y);
      a1[6] = (short)f2bf(w1.z); a1[7] = (short)f2bf(w1.w);
      #pragma unroll
      for (int nt = 0; nt < 8; ++nt) {
        bf16x8 b = *(const bf16x8*)(smem + ((ksl * 8 + nt) * 64 + l) * 16);
        acc[0][nt] = __builtin_amdgcn_mfma_f32_16x16x32_bf16(a0, b, acc[0][nt], 0, 0, 0);
        acc[1][nt] = __builtin_amdgcn_mfma_f32_16x16x32_bf16(a1, b, acc[1][nt], 0, 0, 0);
      }
    }
  }
  __syncthreads();  // B dead; per-wave epilogue scratch (8KB each)
  if (!second) {
    uint8_t* lds8 = (uint8_t*)(smem + wid * 8192);
    epilogue_fp8(acc[0], l, r0, lds8, H8, dinv);
    epilogue_fp8(acc[1], l, r0 + 16, lds8, H8, dinv);
  } else {
    uint16_t* ldsb = (uint16_t*)(smem + wid * 8192);
    #pragma unroll
    for (int rt = 0; rt < 2; ++rt) {
      int row0 = r0 + rt * 16;
      #pragma unroll
      for (int nt = 0; nt < 8; ++nt)
        #pragma unroll
        for (int j = 0; j < 4; ++j)
          ldsb[((l >> 4) * 4 + j) * 128 + nt * 16 + (l & 15)] = (uint16_t)f2bf(acc[rt][nt][j]);
      asm volatile("s_waitcnt lgkmcnt(0)" ::: "memory");
      const uint4* sb = (const uint4*)ldsb;
      if (row0 + (l >> 2) < N_NODES) {
        uint4* gb = (uint4*)(resB + (size_t)(row0 + (l >> 2)) * 128 + (l & 3) * 32);
        #pragma unroll
        for (int t = 0; t < 4; ++t) gb[t] = sb[l * 4 + t];
      }
      asm volatile("s_waitcnt lgkmcnt(0)" ::: "memory");
    }
  }
}

// layers 1/2 GEMM: A bf16 [N][128] @ Wp(LDS-shared) -> fp8 h'
__global__ __launch_bounds__(256) void k_gemm8(const uint16_t* __restrict__ A,
                                               const uint16_t* __restrict__ Wp,
                                               uint8_t* __restrict__ H8,
                                               const float* __restrict__ dinv) {
  __shared__ __align__(16) char smem[32768];
  int tid = threadIdx.x, wid = tid >> 6, l = tid & 63;
  #pragma unroll
  for (int i = 0; i < 8; ++i) {
    int gidx = i * 256 + tid;
    *(uint4*)(smem + gidx * 16) = *(const uint4*)((const char*)Wp + gidx * 16);
  }
  __syncthreads();
  int r0 = blockIdx.x * 128 + wid * 32;
  int hk = l >> 4, rl = l & 15;
  int ra0 = min(r0 + rl, N_NODES - 1);
  int ra1 = min(r0 + 16 + rl, N_NODES - 1);
  f32x4 acc[2][8] = {};
  #pragma unroll
  for (int ks = 0; ks < 4; ++ks) {
    bf16x8 a0 = *(const bf16x8*)(A + (size_t)ra0 * 128 + ks * 32 + hk * 8);
    bf16x8 a1 = *(const bf16x8*)(A + (size_t)ra1 * 128 + ks * 32 + hk * 8);
    #pragma unroll
    for (int nt = 0; nt < 8; ++nt) {
      bf16x8 b = *(const bf16x8*)(smem + ((ks * 8 + nt) * 64 + l) * 16);
      acc[0][nt] = __builtin_amdgcn_mfma_f32_16x16x32_bf16(a0, b, acc[0][nt], 0, 0, 0);
      acc[1][nt] = __builtin_amdgcn_mfma_f32_16x16x32_bf16(a1, b, acc[1][nt], 0, 0, 0);
    }
  }
  __syncthreads();  // B dead; reuse as epilogue scratch
  uint8_t* lds8 = (uint8_t*)(smem + wid * 4096);
  epilogue_fp8(acc[0], l, r0, lds8, H8, dinv);
  epilogue_fp8(acc[1], l, r0 + 16, lds8, H8, dinv);
}

// fused: fp8 gather-sum + bias + LN + ReLU + bf16 residual
// four 16-lane quarters; quarter q owns 4-edge blocks jb%4==q (uint4 index loads);
// lane owns 8 channels (uint2 gather); unweighted fp8 row sum (scales pre-folded).
#define PROC(hx, hy)                                                   \
  do {                                                                 \
    f32x2 f_;                                                          \
    f_ = __builtin_amdgcn_cvt_pk_f32_fp8((hx), false);                 \
    asm("v_pk_add_f32 %0, %0, %1" : "+v"(A01) : "v"(f_));              \
    f_ = __builtin_amdgcn_cvt_pk_f32_fp8((hx), true);                  \
    asm("v_pk_add_f32 %0, %0, %1" : "+v"(A23) : "v"(f_));              \
    f_ = __builtin_amdgcn_cvt_pk_f32_fp8((hy), false);                 \
    asm("v_pk_add_f32 %0, %0, %1" : "+v"(A45) : "v"(f_));              \
    f_ = __builtin_amdgcn_cvt_pk_f32_fp8((hy), true);                  \
    asm("v_pk_add_f32 %0, %0, %1" : "+v"(A67) : "v"(f_));              \
  } while (0)

__global__ __launch_bounds__(256) void k_agg(const uint8_t* __restrict__ H8,
                                             const int* __restrict__ sedge,
                                             const int2* __restrict__ offs2,
                                             const float* __restrict__ dinv,
                                             const float* __restrict__ bias,
                                             const float* __restrict__ g,
                                             const float* __restrict__ be,
                                             const uint16_t* __restrict__ residB,
                                             float* __restrict__ outF,
                                             uint16_t* __restrict__ outB) {
  int wid = threadIdx.x >> 6, l = threadIdx.x & 63;
  int v = blockIdx.x * 4 + wid;
  if (v >= N_NODES) return;
  int q = l >> 4, c = l & 15;
  uint32_t coff = (uint32_t)c << 3;
  f32x2 A01 = {0.f, 0.f}, A23 = {0.f, 0.f}, A45 = {0.f, 0.f}, A67 = {0.f, 0.f};
  int2 o = offs2[v];
  int nb = o.y;                          // 4-edge blocks (padded, exact)
  const uint4* sblk = (const uint4*)(sedge + o.x);
  int jb = q;
  for (; jb + 4 < nb; jb += 8) {
    uint4 i0 = sblk[jb];
    uint4 i1 = sblk[jb + 4];
    uint2 h0 = *(const uint2*)(H8 + ((i0.x << 7) | coff));
    uint2 h1 = *(const uint2*)(H8 + ((i0.y << 7) | coff));
    uint2 h2 = *(const uint2*)(H8 + ((i0.z << 7) | coff));
    uint2 h3 = *(const uint2*)(H8 + ((i0.w << 7) | coff));
    uint2 h4 = *(const uint2*)(H8 + ((i1.x << 7) | coff));
    uint2 h5 = *(const uint2*)(H8 + ((i1.y << 7) | coff));
    uint2 h6 = *(const uint2*)(H8 + ((i1.z << 7) | coff));
    uint2 h7 = *(const uint2*)(H8 + ((i1.w << 7) | coff));
    PROC(h0.x, h0.y); PROC(h1.x, h1.y); PROC(h2.x, h2.y); PROC(h3.x, h3.y);
    PROC(h4.x, h4.y); PROC(h5.x, h5.y); PROC(h6.x, h6.y); PROC(h7.x, h7.y);
  }
  for (; jb < nb; jb += 4) {
    uint4 i0 = sblk[jb];
    uint2 h0 = *(const uint2*)(H8 + ((i0.x << 7) | coff));
    uint2 h1 = *(const uint2*)(H8 + ((i0.y << 7) | coff));
    uint2 h2 = *(const uint2*)(H8 + ((i0.z << 7) | coff));
    uint2 h3 = *(const uint2*)(H8 + ((i0.w << 7) | coff));
    PROC(h0.x, h0.y); PROC(h1.x, h1.y); PROC(h2.x, h2.y); PROC(h3.x, h3.y);
  }
  if (q == 0) {  // self loop: + own h' row
    uint2 h = *(const uint2*)(H8 + (((uint32_t)v << 7) | coff));
    PROC(h.x, h.y);
  }
  // combine the 4 quarters
  float a0 = A01.x, a1 = A01.y, a2 = A23.x, a3 = A23.y;
  float a4 = A45.x, a5 = A45.y, a6 = A67.x, a7 = A67.y;
  #pragma unroll
  for (int m = 16; m <= 32; m <<= 1) {
    a0 += __shfl_xor(a0, m, 64); a1 += __shfl_xor(a1, m, 64);
    a2 += __shfl_xor(a2, m, 64); a3 += __shfl_xor(a3, m, 64);
    a4 += __shfl_xor(a4, m, 64); a5 += __shfl_xor(a5, m, 64);
    a6 += __shfl_xor(a6, m, 64); a7 += __shfl_xor(a7, m, 64);
  }
  float dv = dinv[v];
  float4 bb0 = *(const float4*)(bias + 8 * c);
  float4 bb1 = *(const float4*)(bias + 8 * c + 4);
  a0 = dv * a0 + bb0.x; a1 = dv * a1 + bb0.y;
  a2 = dv * a2 + bb0.z; a3 = dv * a3 + bb0.w;
  a4 = dv * a4 + bb1.x; a5 = dv * a5 + bb1.y;
  a6 = dv * a6 + bb1.z; a7 = dv * a7 + bb1.w;
  // LayerNorm over 128 channels (16-lane reduction, replicated across quarters)
  float s = a0 + a1 + a2 + a3 + a4 + a5 + a6 + a7;
  #pragma unroll
  for (int m = 1; m < 16; m <<= 1) s += __shfl_xor(s, m, 64);
  float mu = s * (1.f / 128.f);
  float d0 = a0 - mu, d1 = a1 - mu, d2 = a2 - mu, d3 = a3 - mu;
  float d4 = a4 - mu, d5 = a5 - mu, d6 = a6 - mu, d7 = a7 - mu;
  float qq = d0 * d0 + d1 * d1 + d2 * d2 + d3 * d3 +
             d4 * d4 + d5 * d5 + d6 * d6 + d7 * d7;
  #pragma unroll
  for (int m = 1; m < 16; m <<= 1) qq += __shfl_xor(qq, m, 64);
  float rs = rsqrtf(qq * (1.f / 128.f) + EPS);
  float4 gg0 = *(const float4*)(g + 8 * c);
  float4 gg1 = *(const float4*)(g + 8 * c + 4);
  float4 ee0 = *(const float4*)(be + 8 * c);
  float4 ee1 = *(const float4*)(be + 8 * c + 4);
  float y0 = fmaxf(d0 * rs * gg0.x + ee0.x, 0.f);
  float y1 = fmaxf(d1 * rs * gg0.y + ee0.y, 0.f);
  float y2 = fmaxf(d2 * rs * gg0.z + ee0.z, 0.f);
  float y3 = fmaxf(d3 * rs * gg0.w + ee0.w, 0.f);
  float y4 = fmaxf(d4 * rs * gg1.x + ee1.x, 0.f);
  float y5 = fmaxf(d5 * rs * gg1.y + ee1.y, 0.f);
  float y6 = fmaxf(d6 * rs * gg1.z + ee1.z, 0.f);
  float y7 = fmaxf(d7 * rs * gg1.w + ee1.w, 0.f);
  uint4 rr = *(const uint4*)(residB + (size_t)v * 128 + 8 * c);
  y0 += bflo(rr.x); y1 += bfhi(rr.x);
  y2 += bflo(rr.y); y3 += bfhi(rr.y);
  y4 += bflo(rr.z); y5 += bfhi(rr.z);
  y6 += bflo(rr.w); y7 += bfhi(rr.w);
  if (q == 0) {
    if (outF) {
      float* op = outF + (size_t)v * HID + 8 * c;
      *(float4*)op = make_float4(y0, y1, y2, y3);
      *(float4*)(op + 4) = make_float4(y4, y5, y6, y7);
    }
    if (outB) {
      uint4 oo;
      oo.x = f2bf(y0) | (f2bf(y1) << 16);
      oo.y = f2bf(y2) | (f2bf(y3) << 16);
      oo.z = f2bf(y4) | (f2bf(y5) << 16);
      oo.w = f2bf(y6) | (f2bf(y7) << 16);
      *(uint4*)(outB + (size_t)v * 128 + 8 * c) = oo;
    }
  }
}

extern "C" void kernel_launch(void* const* d_in, const int* in_sizes, int n_in,
                              void* d_out, int out_size, void* d_ws, size_t ws_size,
                              hipStream_t stream) {
  const float* x   = (const float*)d_in[0];
  const void*  ei  = d_in[1];
  const float* W0  = (const float*)d_in[2];
  const float* b0  = (const float*)d_in[3];
  const float* g0  = (const float*)d_in[4];
  const float* be0 = (const float*)d_in[5];
  const float* W1  = (const float*)d_in[6];
  const float* b1  = (const float*)d_in[7];
  const float* g1  = (const float*)d_in[8];
  const float* be1 = (const float*)d_in[9];
  const float* W2  = (const float*)d_in[10];
  const float* b2  = (const float*)d_in[11];
  const float* g2  = (const float*)d_in[12];
  const float* be2 = (const float*)d_in[13];
  const float* Wr  = (const float*)d_in[14];

  char* ws = (char*)d_ws;
  int*      sedge  = (int*)(ws + OFF_SRC);
  int2*     offs2  = (int2*)(ws + OFF_OFFS2);
  float*    dinv   = (float*)(ws + OFF_DINV);
  uint16_t* wpk0   = (uint16_t*)(ws + OFF_WPK0);
  uint16_t* wpk1   = (uint16_t*)(ws + OFF_WPK1);
  uint16_t* wpk2   = (uint16_t*)(ws + OFF_WPK2);
  uint16_t* wpkr   = (uint16_t*)(ws + OFF_WPKR);
  int*      flag   = (int*)(ws + OFF_FLAG);
  int*      bcur   = (int*)(ws + OFF_BCUR);
  uint8_t*  h8     = (uint8_t*)(ws + OFF_H8);
  int2*     part   = (int2*)(ws + OFF_PART);
  uint16_t* resB   = (uint16_t*)(ws + OFF_RESB);
  uint16_t* hbA    = (uint16_t*)(ws + OFF_HBA);
  uint16_t* hbB    = (uint16_t*)(ws + OFF_HBB);
  float*    out    = (float*)d_out;

  // ---- edge preprocessing: partition (fixed-cap buckets) -> fused bucket CSR ----
  k_flag<<<1, 256, 0, stream>>>((const uint32_t*)ei, flag);
  k_init<<<1, 256, 0, stream>>>(bcur);
  k_part<<<(N_EDGES + PCHUNK - 1) / PCHUNK, 256, 0, stream>>>(ei, flag, bcur, part);
  k_bucket<<<NBUK, 256, 0, stream>>>(part, bcur, offs2, dinv, sedge);
  // sentinel row (src == N_NODES) must be zero; part buffer is dead now
  hipMemsetAsync(h8 + (size_t)N_NODES * 128, 0, 128, stream);

  // ---- weight packing ----
  k_packW<<<16, 256, 0, stream>>>(W0, wpk0, IN_CH);
  k_packW<<<8, 256, 0, stream>>>(W1, wpk1, HID);
  k_packW<<<8, 256, 0, stream>>>(W2, wpk2, HID);
  k_packW<<<16, 256, 0, stream>>>(Wr, wpkr, IN_CH);

  // ---- layer 0: fused dual K=256 GEMM launch (x@W0 -> fp8 h', x@Wr -> bf16 resid) ----
  k_gemm0d<<<2 * GEMM_GRID, 256, 0, stream>>>(x, wpk0, wpkr, h8, dinv, resB);
  k_agg<<<25000, 256, 0, stream>>>(h8, sedge, offs2, dinv, b0, g0, be0, resB, nullptr, hbA);

  // ---- layer 1 ----
  k_gemm8<<<GEMM_GRID, 256, 0, stream>>>(hbA, wpk1, h8, dinv);
  k_agg<<<25000, 256, 0, stream>>>(h8, sedge, offs2, dinv, b1, g1, be1, hbA, nullptr, hbB);

  // ---- layer 2 (writes d_out f32) ----
  k_gemm8<<<GEMM_GRID, 256, 0, stream>>>(hbB, wpk2, h8, dinv);
  k_agg<<<25000, 256, 0, stream>>>(h8, sedge, offs2, dinv, b2, g2, be2, hbB, out, nullptr);

  (void)in_sizes; (void)n_in; (void)out_size; (void)ws_size;
}